// Round 7
// baseline (8889.054 us; speedup 1.0000x reference)
//
#include <hip/hip_runtime.h>

#define NB 128
#define NT 512
#define NE 256
#define NH 512
#define NA 64
#define NG 8
#define GB 16

typedef short bf16x8 __attribute__((ext_vector_type(8)));
typedef float f32x4 __attribute__((ext_vector_type(4)));
typedef unsigned short u16x8 __attribute__((ext_vector_type(8)));
typedef unsigned long long u64;

__device__ __forceinline__ unsigned short f2bf(float f){
  unsigned u = __builtin_bit_cast(unsigned, f);
  u = u + 0x7fffu + ((u >> 16) & 1u);
  return (unsigned short)(u >> 16);
}
__device__ __forceinline__ float bf2f(unsigned short h){
  unsigned u = ((unsigned)h) << 16;
  return __builtin_bit_cast(float, u);
}
__device__ __forceinline__ bf16x8 packbf2(f32x4 a, f32x4 b){
  bf16x8 r;
  r[0]=(short)f2bf(a[0]); r[1]=(short)f2bf(a[1]); r[2]=(short)f2bf(a[2]); r[3]=(short)f2bf(a[3]);
  r[4]=(short)f2bf(b[0]); r[5]=(short)f2bf(b[1]); r[6]=(short)f2bf(b[2]); r[7]=(short)f2bf(b[3]);
  return r;
}
__device__ __forceinline__ bf16x8 loadB_f32(const float* p){
  f32x4 a = *(const f32x4*)p;
  f32x4 b = *(const f32x4*)(p + 4);
  return packbf2(a, b);
}
#define MFMA(a,b,c) __builtin_amdgcn_mfma_f32_16x16x32_bf16(a,b,c,0,0,0)

__device__ __forceinline__ float fsig(float x){
  return __builtin_amdgcn_rcpf(1.f + __expf(-x));
}
__device__ __forceinline__ float ftanh(float x){
  float e2 = __expf(2.f * x);
  return 1.f - 2.f * __builtin_amdgcn_rcpf(e2 + 1.f);
}

// s_sleep needs a CONSTANT immediate: constant-ladder backoff.
__device__ __forceinline__ void sleep_bk(int bk){
  if (bk <= 0)      __builtin_amdgcn_s_sleep(1);
  else if (bk == 1) __builtin_amdgcn_s_sleep(2);
  else if (bk == 2) __builtin_amdgcn_s_sleep(4);
  else              __builtin_amdgcn_s_sleep(8);
}

// ---- MALL seq-tagged slot protocol (proven rounds 0-6) ----
// unit u64 = {seq:32 | payload}. Producers fire-and-forget via agent-scope
// atomic exchange; consumers poll the data itself until tags match (detection
// overlaps transfer). Backoff keeps retry traffic off the LLC queues.
__device__ __forceinline__ u64 aload(const u64* p){
  return __hip_atomic_load(p, __ATOMIC_RELAXED, __HIP_MEMORY_SCOPE_AGENT);
}
__device__ __forceinline__ void fire(u64* p, u64 v){
  (void)__hip_atomic_exchange(p, v, __ATOMIC_RELAXED, __HIP_MEMORY_SCOPE_AGENT);
}
__device__ __forceinline__ u64 packh(unsigned sq, float a, float b){
  return ((u64)sq << 32) | ((u64)f2bf(b) << 16) | (u64)f2bf(a);
}
__device__ __forceinline__ u64 packf(unsigned sq, float a){
  return ((u64)sq << 32) | (u64)__builtin_bit_cast(unsigned, a);
}

// ---------------------------------------------------------------------------
// Pre-pass: tp[pos][a] = (embedding[token] . Wt[a,:]) + bt[a], stored bf16.
// ---------------------------------------------------------------------------
__global__ __launch_bounds__(256) void k_tp(
    const int* __restrict__ tok, const float* __restrict__ emb,
    const float* __restrict__ Wt, const float* __restrict__ bt,
    unsigned short* __restrict__ tp)
{
  const int lane = threadIdx.x & 63;
  const int w = threadIdx.x >> 6;
  const int m16 = lane & 15, quad = lane >> 4;

  bf16x8 wfq[8][4];
#pragma unroll
  for (int kc = 0; kc < 8; kc++)
#pragma unroll
    for (int nt = 0; nt < 4; nt++)
      wfq[kc][nt] = loadB_f32(Wt + (nt*16 + m16)*NE + kc*32 + quad*8);

  float btv[4];
#pragma unroll
  for (int nt = 0; nt < 4; nt++) btv[nt] = bt[nt*16 + m16];

  const int gw = blockIdx.x * 4 + w;
#pragma unroll 1
  for (int it = 0; it < 4; it++){
    const int pt = gw * 4 + it;
    const int pos = pt*16 + m16;
    const long row = (long)tok[pos];
    const float* xrow = emb + row * NE;
    f32x4 acc[4] = {{0,0,0,0},{0,0,0,0},{0,0,0,0},{0,0,0,0}};
#pragma unroll
    for (int kc = 0; kc < 8; kc++){
      bf16x8 af = loadB_f32(xrow + kc*32 + quad*8);
#pragma unroll
      for (int nt = 0; nt < 4; nt++)
        acc[nt] = MFMA(af, wfq[kc][nt], acc[nt]);
    }
#pragma unroll
    for (int nt = 0; nt < 4; nt++)
#pragma unroll
      for (int r = 0; r < 4; r++){
        int posr = pt*16 + quad*4 + r;
        tp[(long)posr * NA + nt*16 + m16] = f2bf(acc[nt][r] + btv[nt]);
      }
  }
}

// ---------------------------------------------------------------------------
// Pre-pass 2: pack Wq into bf16 MFMA A-fragment blob.
// ---------------------------------------------------------------------------
__global__ __launch_bounds__(256) void k_pack(
    const float* __restrict__ Wq, unsigned short* __restrict__ blob)
{
  const int lane = threadIdx.x & 63, wv = threadIdx.x >> 6;
  const int m16 = lane & 15, quad = lane >> 4;
#pragma unroll
  for (int kc = 0; kc < 16; kc++){
    bf16x8 t = loadB_f32(Wq + (long)(wv*16 + m16)*NH + kc*32 + quad*8);
    *(bf16x8*)&blob[((wv*16 + kc)*64 + lane)*8] = t;
  }
}

// ---------------------------------------------------------------------------
struct KArgs {
  const int* len;
  const float* bq; const float* v; const float* bv;
  const float* Wih0; const float* Whh0; const float* bih0; const float* bhh0;
  const float* Wih1; const float* Whh1; const float* bih1; const float* bhh1;
  const unsigned short* tp;
  const unsigned short* wqblob;
  u64* hbuf;   // per group: [state*2+par][4096] u64; unit idx(dp,b)=(dp>>2)*64+b*4+(dp&3)
  u64* cbuf;   // per group: [par][16 batch][72] u64, unit={seq32,f32}
  float* out;
};

// Poll+stage a 512x16 bf16 h-state into fragment-ordered LDS [kc][lane][8].
// 512 threads x 8 contiguous u64 (two 32B segments) -> the ENTIRE 16KB state
// is detected+transferred in ONE dependent round-trip (was 4 serial rounds).
__device__ __forceinline__ void stage_load(const u64* __restrict__ buf, unsigned sq,
                                           unsigned short (*hs)[64][8], int tid){
  const int lane = tid & 63, w8 = tid >> 6;          // w8 in 0..7
  const int b = lane & 15, q8 = lane >> 4;
  const u64* uA = buf + ((w8*2+0)*4 + q8)*64 + b*4;
  const u64* uB = buf + ((w8*2+1)*4 + q8)*64 + b*4;
  u64 x[8];
  int bk = 0;
  for (;;){
    bool ok = true;
#pragma unroll
    for (int j = 0; j < 4; j++) x[j]   = aload(uA + j);
#pragma unroll
    for (int j = 0; j < 4; j++) x[4+j] = aload(uB + j);
#pragma unroll
    for (int j = 0; j < 8; j++) ok &= ((unsigned)(x[j]>>32) == sq);
    if (ok) break;
    sleep_bk(bk);
    if (bk < 3) bk++;
  }
  u16x8 dA, dB;
#pragma unroll
  for (int j = 0; j < 4; j++){
    dA[2*j]   = (unsigned short)x[j];
    dA[2*j+1] = (unsigned short)(x[j] >> 16);
    dB[2*j]   = (unsigned short)x[4+j];
    dB[2*j+1] = (unsigned short)(x[4+j] >> 16);
  }
  *(u16x8*)&hs[w8*2+0][lane][0] = dA;
  *(u16x8*)&hs[w8*2+1][lane][0] = dB;
}

// Group = 16 WGs x 8 waves. Waves 0..5 compute rows (w%3 = gate matrix slice,
// w/3 = 16-dim block within the WG's 32 dims); waves 6..7 combine + publish.
// Attention: one batch per WG (batch = m), all 8 waves, chunk phase = w.
__global__ __launch_bounds__(512, 1) void k_main(KArgs A_)
{
  const int tid = threadIdx.x, lane = tid & 63, w = tid >> 6;   // w 0..7
  const int g = blockIdx.x & 7, m = blockIdx.x >> 3;            // m 0..15
  const int m16 = lane & 15, quad = lane >> 4;

  __shared__ __attribute__((aligned(16))) unsigned short h0s[16][64][8]; // 16KB
  __shared__ __attribute__((aligned(16))) unsigned short h1s[16][64][8]; // 16KB
  __shared__ __attribute__((aligned(16))) float dslab[6][512];           // 12KB gate staging
  __shared__ __attribute__((aligned(16))) float qs[16][68];              // q[b][a]
  __shared__ __attribute__((aligned(16))) float cslab[8][64];            // per-wave ctx partials
  __shared__ float cden[8];
  __shared__ __attribute__((aligned(16))) unsigned short ctxf[64][16];   // scaled ctx B-frags

  u64* hb = A_.hbuf + (long)g * (4*4096);        // [h0 p0|h0 p1|h1 p0|h1 p1]
  u64* cb = A_.cbuf + (long)g * (2*16*72);       // [par][b][72]
  const int b0 = g * GB;

  // ----- persistent weight fragments (w<6): wf[0..15]=Whh0, [16..31]=Whh1,
  //       [32..47]=Wih1, rows (w%3)*512 + m*32 + (w/3)*16 -----
  bf16x8 wf[48], wih0f[2];
  float bhh0v[4], bih0v[4], bhh1v[4], bih1v[4];
  if (w < 6){
    const int r0 = (w % 3) * NH + m * 32 + (w / 3) * 16;
#pragma unroll
    for (int kc = 0; kc < 16; kc++){
      wf[kc]    = loadB_f32(A_.Whh0 + (long)(r0 + m16)*NH + kc*32 + quad*8);
      wf[16+kc] = loadB_f32(A_.Whh1 + (long)(r0 + m16)*NH + kc*32 + quad*8);
      wf[32+kc] = loadB_f32(A_.Wih1 + (long)(r0 + m16)*NH + kc*32 + quad*8);
    }
#pragma unroll
    for (int kc = 0; kc < 2; kc++)
      wih0f[kc] = loadB_f32(A_.Wih0 + (r0 + m16)*NA + kc*32 + quad*8);
#pragma unroll
    for (int r = 0; r < 4; r++){
      int d = r0 + quad*4 + r;
      bhh0v[r] = A_.bhh0[d]; bih0v[r] = A_.bih0[d];
      bhh1v[r] = A_.bhh1[d]; bih1v[r] = A_.bih1[d];
    }
  }
  float bqw[4];
#pragma unroll
  for (int r = 0; r < 4; r++) bqw[r] = A_.bq[(w & 3)*16 + quad*4 + r];

  float vv[16];
#pragma unroll
  for (int jj = 0; jj < 16; jj++) vv[jj] = A_.v[quad*16 + jj];
  const float bvv = A_.bv[0];

  int myidx = 0, imax = 0;
#pragma unroll 1
  for (int b = 0; b < GB; b++){
    int L = A_.len[b0 + b];
    int ix = L - 2; ix = ix < 0 ? 0 : (ix > NT-1 ? NT-1 : ix);
    if (b == m16) myidx = ix;
    imax = imax > ix ? imax : ix;
  }

  f32x4 h0p = {0,0,0,0}, h1p = {0,0,0,0};

  // zero LDS h-state so step 0's matmuls yield pure bias (h(-1)=0)
  {
    u16x8 z = {0,0,0,0,0,0,0,0};
#pragma unroll
    for (int c = 0; c < 2; c++){
      int kc = w*2 + c;
      *(u16x8*)&h0s[kc][lane][0] = z;
      *(u16x8*)&h1s[kc][lane][0] = z;
    }
  }
  __syncthreads();

#pragma unroll 1
  for (int i = 0; i <= imax; i++){
    const int par = i & 1;
    const unsigned sq = (unsigned)(i + 1);

    // ============ Phase A: g0 from old h0; stage h1(i-1); q ============
    f32x4 g0 = {0,0,0,0};
    if (w < 6){
#pragma unroll
      for (int kc = 0; kc < 16; kc++){
        bf16x8 h0f = *(const bf16x8*)&h0s[kc][lane][0];
        g0 = MFMA(wf[kc], h0f, g0);
      }
#pragma unroll
      for (int r = 0; r < 4; r++) g0[r] += bhh0v[r];
    }
    if (i > 0)
      stage_load(hb + (long)(2 + ((i-1)&1))*4096, (unsigned)i, h1s, tid);
    __syncthreads();   // h1s ready
    if (w < 4){
      f32x4 qa = {0,0,0,0};
#pragma unroll
      for (int kc = 0; kc < 16; kc++){
        bf16x8 b1f = *(const bf16x8*)&h1s[kc][lane][0];
        bf16x8 af = *(const bf16x8*)&A_.wqblob[((w*16 + kc)*64 + lane)*8];
        qa = MFMA(af, b1f, qa);
      }
#pragma unroll
      for (int r = 0; r < 4; r++)
        qs[m16][w*16 + quad*4 + r] = qa[r] + bqw[r];
    }
    __syncthreads();   // q ready

    // ============ Phase B: attention for batch m, chunk phase w ============
    {
      float qv[16];
#pragma unroll
      for (int jq = 0; jq < 4; jq++){
        f32x4 t = *(const f32x4*)&qs[m][quad*16 + jq*4];
        qv[jq*4+0]=t[0]; qv[jq*4+1]=t[1]; qv[jq*4+2]=t[2]; qv[jq*4+3]=t[3];
      }
      float ctxp[16];
#pragma unroll
      for (int jj = 0; jj < 16; jj++) ctxp[jj] = 0.f;
      float denp = 0.f;
      const unsigned short* tpb = A_.tp + (long)(b0 + m) * NT * NA;
#pragma unroll 1
      for (int c = w; c*16 <= i; c += 8){
        const int t = c*16 + m16;
        const unsigned short* tpp = tpb + (long)t*NA + quad*16;
        u16x8 ta = *(const u16x8*)tpp;
        u16x8 tb = *(const u16x8*)(tpp + 8);
        float tpf[16];
#pragma unroll
        for (int jj = 0; jj < 8; jj++){ tpf[jj] = bf2f(ta[jj]); tpf[8+jj] = bf2f(tb[jj]); }
        float sp = 0.f;
#pragma unroll
        for (int jj = 0; jj < 16; jj++){
          float x = tpf[jj] + qv[jj];
          sp = fmaf(ftanh(x), vv[jj], sp);
        }
        sp += __shfl_xor(sp, 16);
        sp += __shfl_xor(sp, 32);
        float e = __expf(sp + bvv);
        e = (t <= i) ? e : 0.f;
        denp += e;
#pragma unroll
        for (int jj = 0; jj < 16; jj++) ctxp[jj] = fmaf(e, tpf[jj], ctxp[jj]);
      }
#pragma unroll
      for (int off = 1; off < 64; off <<= 1) denp += __shfl_xor(denp, off);
      denp *= 0.25f;
#pragma unroll
      for (int st = 0; st < 4; st++){
        const int bit = 1 << st;
        const bool up = (lane >> st) & 1;
        const int n2 = (16 >> st) >> 1;
#pragma unroll
        for (int j2 = 0; j2 < 8; j2++){
          if (j2 < n2){
            float keep = up ? ctxp[2*j2+1] : ctxp[2*j2];
            float send = up ? ctxp[2*j2]   : ctxp[2*j2+1];
            float got = __shfl_xor(send, bit);
            ctxp[j2] = keep + got;
          }
        }
      }
      cslab[w][lane] = ctxp[0];
      if (lane == 0) cden[w] = denp;
    }
    __syncthreads();   // 8-wave partials in LDS
    if (w == 0){
      float s = cslab[0][lane] + cslab[1][lane] + cslab[2][lane] + cslab[3][lane]
              + cslab[4][lane] + cslab[5][lane] + cslab[6][lane] + cslab[7][lane];
      u64* slot = cb + ((long)par*16 + m)*72;
      fire(slot + lane, packf(sq, s));
      if (lane == 0){
        float dsum = cden[0]+cden[1]+cden[2]+cden[3]+cden[4]+cden[5]+cden[6]+cden[7];
        fire(slot + 64, packf(sq, dsum));
      }
    }

    // ============ Phase C: waves 6,7 poll ctx (lane-parallel, 1 RT) ============
    if (w >= 6){
      const int kc = w - 6;
      const u64* c0 = cb + ((long)par*16 + m16)*72;
      u64 dn, t[8];
      int bk = 0;
      for (;;){
        bool ok = true;
        dn = aload(c0 + 64);
#pragma unroll
        for (int j = 0; j < 8; j++) t[j] = aload(c0 + kc*32 + quad*8 + j);
        ok = ((unsigned)(dn>>32) == sq);
#pragma unroll
        for (int j = 0; j < 8; j++) ok &= ((unsigned)(t[j]>>32) == sq);
        if (ok) break;
        sleep_bk(bk);
        if (bk < 3) bk++;
      }
      const float rdn = __builtin_amdgcn_rcpf(__builtin_bit_cast(float, (unsigned)dn));
      u16x8 f;
#pragma unroll
      for (int j = 0; j < 8; j++)
        f[j] = f2bf(__builtin_bit_cast(float, (unsigned)t[j]) * rdn);
      *(u16x8*)&ctxf[lane][kc*8] = f;
    }
    __syncthreads();   // ctx frags ready
    if (w < 6){
      f32x4 gi0 = {0,0,0,0};
      bf16x8 cf0 = *(const bf16x8*)&ctxf[lane][0];
      bf16x8 cf1 = *(const bf16x8*)&ctxf[lane][8];
      gi0 = MFMA(wih0f[0], cf0, gi0);
      gi0 = MFMA(wih0f[1], cf1, gi0);
#pragma unroll
      for (int r = 0; r < 4; r++) gi0[r] += bih0v[r];
      const int off = (w/3)*256 + lane*4;
      *(f32x4*)&dslab[w%3][off] = g0;
      *(f32x4*)&dslab[3 + w%3][off] = gi0;
    }
    __syncthreads();
    if (w >= 6){
      const int off = (w-6)*256 + lane*4;
      f32x4 ghr = *(f32x4*)&dslab[0][off];
      f32x4 ghz = *(f32x4*)&dslab[1][off];
      f32x4 ghn = *(f32x4*)&dslab[2][off];
      f32x4 gir = *(f32x4*)&dslab[3][off];
      f32x4 giz = *(f32x4*)&dslab[4][off];
      f32x4 gin = *(f32x4*)&dslab[5][off];
      f32x4 hn;
#pragma unroll
      for (int r = 0; r < 4; r++){
        float rr = fsig(gir[r] + ghr[r]);
        float zz = fsig(giz[r] + ghz[r]);
        float nn = ftanh(gin[r] + rr*ghn[r]);
        hn[r] = (1.f - zz)*nn + zz*h0p[r];
      }
      h0p = hn;
      const int dp0 = m*16 + (w-6)*8 + quad*2;
      u64* p0 = hb + (long)par*4096 + (dp0>>2)*64 + m16*4 + (dp0&3);
      fire(p0,     packh(sq, hn[0], hn[1]));
      fire(p0 + 1, packh(sq, hn[2], hn[3]));
    }

    // ============ Phase D: gh1 from old h1; stage h0(i); gi1; combine h1 ======
    f32x4 gh1 = {0,0,0,0};
    if (w < 6){
#pragma unroll
      for (int kc = 0; kc < 16; kc++){
        bf16x8 b1f = *(const bf16x8*)&h1s[kc][lane][0];
        gh1 = MFMA(wf[16+kc], b1f, gh1);
      }
#pragma unroll
      for (int r = 0; r < 4; r++) gh1[r] += bhh1v[r];
    }
    stage_load(hb + (long)par*4096, sq, h0s, tid);
    __syncthreads();
    if (w < 6){
      f32x4 gi1 = {0,0,0,0};
#pragma unroll
      for (int kc = 0; kc < 16; kc++){
        bf16x8 hf = *(const bf16x8*)&h0s[kc][lane][0];
        gi1 = MFMA(wf[32+kc], hf, gi1);
      }
#pragma unroll
      for (int r = 0; r < 4; r++) gi1[r] += bih1v[r];
      const int off = (w/3)*256 + lane*4;
      *(f32x4*)&dslab[w%3][off] = gh1;
      *(f32x4*)&dslab[3 + w%3][off] = gi1;
    }
    __syncthreads();
    if (w >= 6){
      const int off = (w-6)*256 + lane*4;
      f32x4 ghr = *(f32x4*)&dslab[0][off];
      f32x4 ghz = *(f32x4*)&dslab[1][off];
      f32x4 ghn = *(f32x4*)&dslab[2][off];
      f32x4 gir = *(f32x4*)&dslab[3][off];
      f32x4 giz = *(f32x4*)&dslab[4][off];
      f32x4 gin = *(f32x4*)&dslab[5][off];
      f32x4 hn;
#pragma unroll
      for (int r = 0; r < 4; r++){
        float rr = fsig(gir[r] + ghr[r]);
        float zz = fsig(giz[r] + ghz[r]);
        float nn = ftanh(gin[r] + rr*ghn[r]);
        hn[r] = (1.f - zz)*nn + zz*h1p[r];
      }
      h1p = hn;
      const int dp0 = m*16 + (w-6)*8 + quad*2;
      u64* p1 = hb + (long)(2 + par)*4096 + (dp0>>2)*64 + m16*4 + (dp0&3);
      fire(p1,     packh(sq, hn[0], hn[1]));
      fire(p1 + 1, packh(sq, hn[2], hn[3]));
      if (i == myidx)
        *(f32x4*)&A_.out[(long)(b0 + m16)*NH + m*32 + (w-6)*16 + quad*4] = hn;
    }
  }
}

// ---------------------------------------------------------------------------
extern "C" void kernel_launch(void* const* d_in, const int* in_sizes, int n_in,
                              void* d_out, int out_size, void* d_ws, size_t ws_size,
                              hipStream_t stream)
{
  (void)in_sizes; (void)n_in; (void)out_size; (void)ws_size;
  char* ws = (char*)d_ws;
  unsigned short* tp     = (unsigned short*)ws;                    // 8 MB
  unsigned short* wqblob = (unsigned short*)(ws + 8388608);        // 64 KB
  u64* hbuf = (u64*)(ws + 8388608 + 65536);                        // 1 MB
  u64* cbuf = hbuf + 8 * (4*4096);                                 // 144 KB

  // 0xFF-fill all seq-tagged slots: tag 0xFFFFFFFF never matches a target
  // seq (<= 513), so garbage/stale data can never be accepted by a poll.
  (void)hipMemsetAsync(hbuf, 0xFF, (size_t)(8*4*4096 + 8*2*16*72) * sizeof(u64), stream);

  k_tp<<<dim3(256), dim3(256), 0, stream>>>(
      (const int*)d_in[0], (const float*)d_in[2], (const float*)d_in[3],
      (const float*)d_in[4], tp);
  k_pack<<<dim3(1), dim3(256), 0, stream>>>((const float*)d_in[5], wqblob);

  KArgs ka;
  ka.len  = (const int*)d_in[1];
  ka.bq   = (const float*)d_in[6];
  ka.v    = (const float*)d_in[7];  ka.bv   = (const float*)d_in[8];
  ka.Wih0 = (const float*)d_in[9];  ka.Whh0 = (const float*)d_in[10];
  ka.bih0 = (const float*)d_in[11]; ka.bhh0 = (const float*)d_in[12];
  ka.Wih1 = (const float*)d_in[13]; ka.Whh1 = (const float*)d_in[14];
  ka.bih1 = (const float*)d_in[15]; ka.bhh1 = (const float*)d_in[16];
  ka.tp = tp; ka.wqblob = wqblob;
  ka.hbuf = hbuf; ka.cbuf = cbuf;
  ka.out = (float*)d_out;

  k_main<<<dim3(128), dim3(512), 0, stream>>>(ka);
}

// Round 9
// 7737.491 us; speedup vs baseline: 1.1488x; 1.1488x over previous
//
#include <hip/hip_runtime.h>

#define NB 128
#define NT 512
#define NE 256
#define NH 512
#define NA 64
#define NG 8
#define GB 16

typedef short bf16x8 __attribute__((ext_vector_type(8)));
typedef float f32x4 __attribute__((ext_vector_type(4)));
typedef unsigned short u16x8 __attribute__((ext_vector_type(8)));
typedef unsigned long long u64;

__device__ __forceinline__ unsigned short f2bf(float f){
  unsigned u = __builtin_bit_cast(unsigned, f);
  u = u + 0x7fffu + ((u >> 16) & 1u);
  return (unsigned short)(u >> 16);
}
__device__ __forceinline__ float bf2f(unsigned short h){
  unsigned u = ((unsigned)h) << 16;
  return __builtin_bit_cast(float, u);
}
__device__ __forceinline__ bf16x8 packbf2(f32x4 a, f32x4 b){
  bf16x8 r;
  r[0]=(short)f2bf(a[0]); r[1]=(short)f2bf(a[1]); r[2]=(short)f2bf(a[2]); r[3]=(short)f2bf(a[3]);
  r[4]=(short)f2bf(b[0]); r[5]=(short)f2bf(b[1]); r[6]=(short)f2bf(b[2]); r[7]=(short)f2bf(b[3]);
  return r;
}
__device__ __forceinline__ bf16x8 loadB_f32(const float* p){
  f32x4 a = *(const f32x4*)p;
  f32x4 b = *(const f32x4*)(p + 4);
  return packbf2(a, b);
}
#define MFMA(a,b,c) __builtin_amdgcn_mfma_f32_16x16x32_bf16(a,b,c,0,0,0)

__device__ __forceinline__ float fsig(float x){
  return __builtin_amdgcn_rcpf(1.f + __expf(-x));
}
__device__ __forceinline__ float ftanh(float x){
  float e2 = __expf(2.f * x);
  return 1.f - 2.f * __builtin_amdgcn_rcpf(e2 + 1.f);
}

// s_sleep needs a CONSTANT immediate: constant-ladder backoff.
__device__ __forceinline__ void sleep_bk(int bk){
  if (bk <= 0)      __builtin_amdgcn_s_sleep(1);
  else if (bk == 1) __builtin_amdgcn_s_sleep(2);
  else if (bk == 2) __builtin_amdgcn_s_sleep(4);
  else              __builtin_amdgcn_s_sleep(8);
}

// ---- MALL seq-tagged slot protocol (proven rounds 0-6) ----
// unit u64 = {seq:32 | payload}. Producers fire-and-forget via agent-scope
// atomic exchange; consumers poll the data itself until tags match (detection
// overlaps transfer). All loads of one attempt are issued IN FLIGHT TOGETHER
// so each poll attempt costs one dependent round-trip, not several.
__device__ __forceinline__ u64 aload(const u64* p){
  return __hip_atomic_load(p, __ATOMIC_RELAXED, __HIP_MEMORY_SCOPE_AGENT);
}
__device__ __forceinline__ void fire(u64* p, u64 v){
  (void)__hip_atomic_exchange(p, v, __ATOMIC_RELAXED, __HIP_MEMORY_SCOPE_AGENT);
}
__device__ __forceinline__ u64 packh(unsigned sq, float a, float b){
  return ((u64)sq << 32) | ((u64)f2bf(b) << 16) | (u64)f2bf(a);
}
__device__ __forceinline__ u64 packf(unsigned sq, float a){
  return ((u64)sq << 32) | (u64)__builtin_bit_cast(unsigned, a);
}

// ---------------------------------------------------------------------------
// Pre-pass: tp[pos][a] = (embedding[token] . Wt[a,:]) + bt[a], stored bf16.
// ---------------------------------------------------------------------------
__global__ __launch_bounds__(256) void k_tp(
    const int* __restrict__ tok, const float* __restrict__ emb,
    const float* __restrict__ Wt, const float* __restrict__ bt,
    unsigned short* __restrict__ tp)
{
  const int lane = threadIdx.x & 63;
  const int w = threadIdx.x >> 6;
  const int m16 = lane & 15, quad = lane >> 4;

  bf16x8 wfq[8][4];
#pragma unroll
  for (int kc = 0; kc < 8; kc++)
#pragma unroll
    for (int nt = 0; nt < 4; nt++)
      wfq[kc][nt] = loadB_f32(Wt + (nt*16 + m16)*NE + kc*32 + quad*8);

  float btv[4];
#pragma unroll
  for (int nt = 0; nt < 4; nt++) btv[nt] = bt[nt*16 + m16];

  const int gw = blockIdx.x * 4 + w;
#pragma unroll 1
  for (int it = 0; it < 4; it++){
    const int pt = gw * 4 + it;
    const int pos = pt*16 + m16;
    const long row = (long)tok[pos];
    const float* xrow = emb + row * NE;
    f32x4 acc[4] = {{0,0,0,0},{0,0,0,0},{0,0,0,0},{0,0,0,0}};
#pragma unroll
    for (int kc = 0; kc < 8; kc++){
      bf16x8 af = loadB_f32(xrow + kc*32 + quad*8);
#pragma unroll
      for (int nt = 0; nt < 4; nt++)
        acc[nt] = MFMA(af, wfq[kc][nt], acc[nt]);
    }
#pragma unroll
    for (int nt = 0; nt < 4; nt++)
#pragma unroll
      for (int r = 0; r < 4; r++){
        int posr = pt*16 + quad*4 + r;
        tp[(long)posr * NA + nt*16 + m16] = f2bf(acc[nt][r] + btv[nt]);
      }
  }
}

// ---------------------------------------------------------------------------
// Pre-pass 2: pack Wq into bf16 MFMA A-fragment blob.
// ---------------------------------------------------------------------------
__global__ __launch_bounds__(256) void k_pack(
    const float* __restrict__ Wq, unsigned short* __restrict__ blob)
{
  const int lane = threadIdx.x & 63, wv = threadIdx.x >> 6;
  const int m16 = lane & 15, quad = lane >> 4;
#pragma unroll
  for (int kc = 0; kc < 16; kc++){
    bf16x8 t = loadB_f32(Wq + (long)(wv*16 + m16)*NH + kc*32 + quad*8);
    *(bf16x8*)&blob[((wv*16 + kc)*64 + lane)*8] = t;
  }
}

// ---------------------------------------------------------------------------
struct KArgs {
  const int* len;
  const float* bq; const float* v; const float* bv;
  const float* Wih0; const float* Whh0; const float* bih0; const float* bhh0;
  const float* Wih1; const float* Whh1; const float* bih1; const float* bhh1;
  const unsigned short* tp;
  const unsigned short* wqblob;
  u64* hbuf;   // per group: [state*2+par][4096] u64; unit idx(dp,b)=(dp>>2)*64+b*4+(dp&3)
  u64* cbuf;   // per group: [par][half][16 batch][72] u64, unit={seq32,f32}
  float* out;
};

// Poll+stage a 512x16 bf16 h-state into fragment-ordered LDS [kc][lane][8].
// SINGLE poll round: all 16 units (4 per kc-sub-block x 4 kc) issued in flight
// per attempt -> one dependent MALL round-trip instead of 4 serial rounds.
__device__ __forceinline__ void stage_load(const u64* __restrict__ buf, unsigned sq,
                                           unsigned short (*hs)[64][8], int tid){
  const int lane = tid & 63, wv = tid >> 6;
  const int b = lane & 15, q8 = lane >> 4;
  u64 x[16];
  int bk = 0;
  for (;;){
    bool ok = true;
#pragma unroll
    for (int c = 0; c < 4; c++){
      const u64* u0 = buf + ((wv*4 + c)*4 + q8)*64 + b*4;
#pragma unroll
      for (int j = 0; j < 4; j++) x[c*4 + j] = aload(u0 + j);
    }
#pragma unroll
    for (int t = 0; t < 16; t++) ok &= ((unsigned)(x[t] >> 32) == sq);
    if (ok) break;
    sleep_bk(bk);
    if (bk < 3) bk++;
  }
#pragma unroll
  for (int c = 0; c < 4; c++){
    u16x8 d;
#pragma unroll
    for (int j = 0; j < 4; j++){
      d[2*j]   = (unsigned short)x[c*4 + j];
      d[2*j+1] = (unsigned short)(x[c*4 + j] >> 16);
    }
    *(u16x8*)&hs[wv*4 + c][lane][0] = d;
  }
}

__global__ __launch_bounds__(256, 1) void k_main(KArgs A_)
{
  const int tid = threadIdx.x, lane = tid & 63, w = tid >> 6;
  const int g = blockIdx.x & 7, m = blockIdx.x >> 3;   // group, member
  const int m16 = lane & 15, quad = lane >> 4;

  __shared__ __attribute__((aligned(16))) unsigned short h0s[16][64][8]; // 16KB
  __shared__ __attribute__((aligned(16))) unsigned short h1s[16][64][8]; // 16KB
  __shared__ __attribute__((aligned(16))) float dslab[6][256];           // gate staging
  __shared__ __attribute__((aligned(16))) float qs[16][68];              // q[b][a]
  __shared__ __attribute__((aligned(16))) float cslab[4][64];            // per-wave ctx partials
  __shared__ float cden[4];
  __shared__ __attribute__((aligned(16))) unsigned short ctxf[64][16];   // scaled ctx B-frags

  u64* hb = A_.hbuf + (long)g * (4*4096);        // [h0 p0|h0 p1|h1 p0|h1 p1]
  u64* cb = A_.cbuf + (long)g * (2*2*16*72);     // [par][half][b][72]
  const int b0 = g * GB;

  // ----- persistent weight fragments (w<3): wf[0..15]=Whh0, [16..31]=Whh1,
  //       [32..47]=Wih1, rows w*512 + m*16 -----
  bf16x8 wf[48], wih0f[2];
  float bhh0v[4], bih0v[4], bhh1v[4], bih1v[4];
  if (w < 3){
    const int r0 = w * NH + m * 16;
#pragma unroll
    for (int kc = 0; kc < 16; kc++){
      wf[kc]    = loadB_f32(A_.Whh0 + (long)(r0 + m16)*NH + kc*32 + quad*8);
      wf[16+kc] = loadB_f32(A_.Whh1 + (long)(r0 + m16)*NH + kc*32 + quad*8);
      wf[32+kc] = loadB_f32(A_.Wih1 + (long)(r0 + m16)*NH + kc*32 + quad*8);
    }
#pragma unroll
    for (int kc = 0; kc < 2; kc++)
      wih0f[kc] = loadB_f32(A_.Wih0 + (r0 + m16)*NA + kc*32 + quad*8);
#pragma unroll
    for (int r = 0; r < 4; r++){
      int d = r0 + quad*4 + r;
      bhh0v[r] = A_.bhh0[d]; bih0v[r] = A_.bih0[d];
      bhh1v[r] = A_.bhh1[d]; bih1v[r] = A_.bih1[d];
    }
  }
  float bqw[4];
#pragma unroll
  for (int r = 0; r < 4; r++) bqw[r] = A_.bq[w*16 + quad*4 + r];

  float vv[16];
#pragma unroll
  for (int jj = 0; jj < 16; jj++) vv[jj] = A_.v[quad*16 + jj];
  const float bvv = A_.bv[0];
  const int ab = m >> 1;            // batch owned by WG pair {2ab, 2ab+1}
  const int wr = (m & 1)*4 + w;     // chunk phase 0..7

  int myidx = 0, imax = 0;
#pragma unroll 1
  for (int b = 0; b < GB; b++){
    int L = A_.len[b0 + b];
    int ix = L - 2; ix = ix < 0 ? 0 : (ix > NT-1 ? NT-1 : ix);
    if (b == m16) myidx = ix;
    imax = imax > ix ? imax : ix;
  }

  f32x4 h0p = {0,0,0,0}, h1p = {0,0,0,0};

  // zero LDS h-state so step 0's matmuls yield pure bias (h(-1)=0)
  {
    u16x8 z = {0,0,0,0,0,0,0,0};
#pragma unroll
    for (int c = 0; c < 4; c++){
      int kc = (tid>>6)*4 + c;
      *(u16x8*)&h0s[kc][lane][0] = z;
      *(u16x8*)&h1s[kc][lane][0] = z;
    }
  }
  __syncthreads();

#pragma unroll 1
  for (int i = 0; i <= imax; i++){
    const int par = i & 1;
    const unsigned sq = (unsigned)(i + 1);

    // ============ Phase A ============
    // w<3: g0 = Whh0 . h0(i-1) + bhh0 FIRST (off critical path; h0s still
    // holds h0(i-1)). Then the whole WG stages h1 in one poll round.
    f32x4 g0 = {0,0,0,0};
    if (w < 3){
#pragma unroll
      for (int kc = 0; kc < 16; kc++){
        bf16x8 h0f = *(const bf16x8*)&h0s[kc][lane][0];
        g0 = MFMA(wf[kc], h0f, g0);
      }
#pragma unroll
      for (int r = 0; r < 4; r++) g0[r] += bhh0v[r];
    }
    if (i > 0){
      stage_load(hb + (long)(2 + ((i-1)&1))*4096, (unsigned)i, h1s, tid);
      __syncthreads();
    }
    {
      f32x4 qa = {0,0,0,0};
#pragma unroll
      for (int kc = 0; kc < 16; kc++){
        bf16x8 b1f = *(const bf16x8*)&h1s[kc][lane][0];
        bf16x8 af = *(const bf16x8*)&A_.wqblob[((w*16 + kc)*64 + lane)*8];
        qa = MFMA(af, b1f, qa);
      }
#pragma unroll
      for (int r = 0; r < 4; r++)
        qs[m16][w*16 + quad*4 + r] = qa[r] + bqw[r];
    }
    __syncthreads();   // q ready in LDS

    // ============ Phase B: attention for batch ab, chunk phase wr ============
    {
      float qv[16];
#pragma unroll
      for (int jq = 0; jq < 4; jq++){
        f32x4 t = *(const f32x4*)&qs[ab][quad*16 + jq*4];
        qv[jq*4+0]=t[0]; qv[jq*4+1]=t[1]; qv[jq*4+2]=t[2]; qv[jq*4+3]=t[3];
      }
      float ctxp[16];
#pragma unroll
      for (int jj = 0; jj < 16; jj++) ctxp[jj] = 0.f;
      float denp = 0.f;
      const unsigned short* tpb = A_.tp + (long)(b0 + ab) * NT * NA;
#pragma unroll 1
      for (int c = wr; c*16 <= i; c += 8){
        const int t = c*16 + m16;
        const unsigned short* tpp = tpb + (long)t*NA + quad*16;
        u16x8 ta = *(const u16x8*)tpp;
        u16x8 tb = *(const u16x8*)(tpp + 8);
        float tpf[16];
#pragma unroll
        for (int jj = 0; jj < 8; jj++){ tpf[jj] = bf2f(ta[jj]); tpf[8+jj] = bf2f(tb[jj]); }
        float sp = 0.f;
#pragma unroll
        for (int jj = 0; jj < 16; jj++){
          float x = tpf[jj] + qv[jj];
          sp = fmaf(ftanh(x), vv[jj], sp);
        }
        sp += __shfl_xor(sp, 16);
        sp += __shfl_xor(sp, 32);
        float e = __expf(sp + bvv);
        e = (t <= i) ? e : 0.f;
        denp += e;
#pragma unroll
        for (int jj = 0; jj < 16; jj++) ctxp[jj] = fmaf(e, tpf[jj], ctxp[jj]);
      }
#pragma unroll
      for (int off = 1; off < 64; off <<= 1) denp += __shfl_xor(denp, off);
      denp *= 0.25f;
#pragma unroll
      for (int st = 0; st < 4; st++){
        const int bit = 1 << st;
        const bool up = (lane >> st) & 1;
        const int n2 = (16 >> st) >> 1;
#pragma unroll
        for (int j2 = 0; j2 < 8; j2++){
          if (j2 < n2){
            float keep = up ? ctxp[2*j2+1] : ctxp[2*j2];
            float send = up ? ctxp[2*j2]   : ctxp[2*j2+1];
            float got = __shfl_xor(send, bit);
            ctxp[j2] = keep + got;
          }
        }
      }
      cslab[w][lane] = ctxp[0];
      if (lane == 0) cden[w] = denp;
    }
    __syncthreads();   // 4-wave partials in LDS
    if (w == 0){
      float s = cslab[0][lane] + cslab[1][lane] + cslab[2][lane] + cslab[3][lane];
      u64* slot = cb + ((long)(par*2 + (m & 1))*16 + ab)*72;
      fire(slot + lane, packf(sq, s));
      if (lane == 0)
        fire(slot + 64, packf(sq, cden[0]+cden[1]+cden[2]+cden[3]));
    }

    // ============ Phase C: w3 polls ctx — ONE round, 34 loads in flight ======
    if (w == 3){
      const u64* c0 = cb + ((long)(par*2 + 0)*16 + m16)*72;
      const u64* c1 = cb + ((long)(par*2 + 1)*16 + m16)*72;
      u64 d0, d1, t0[16], t1[16];
      int bk = 0;
      for (;;){
        bool ok = true;
        d0 = aload(c0 + 64); d1 = aload(c1 + 64);
#pragma unroll
        for (int kc = 0; kc < 2; kc++){
          const int a0 = kc*32 + quad*8;
#pragma unroll
          for (int j = 0; j < 8; j++){
            t0[kc*8 + j] = aload(c0 + a0 + j);
            t1[kc*8 + j] = aload(c1 + a0 + j);
          }
        }
        ok = ((unsigned)(d0>>32) == sq) & ((unsigned)(d1>>32) == sq);
#pragma unroll
        for (int t = 0; t < 16; t++)
          ok &= ((unsigned)(t0[t]>>32) == sq) & ((unsigned)(t1[t]>>32) == sq);
        if (ok) break;
        sleep_bk(bk);
        if (bk < 3) bk++;
      }
      const float rdn = __builtin_amdgcn_rcpf(
          __builtin_bit_cast(float,(unsigned)d0) + __builtin_bit_cast(float,(unsigned)d1));
#pragma unroll
      for (int kc = 0; kc < 2; kc++){
        u16x8 f;
#pragma unroll
        for (int j = 0; j < 8; j++){
          float s = (__builtin_bit_cast(float,(unsigned)t0[kc*8+j]) +
                     __builtin_bit_cast(float,(unsigned)t1[kc*8+j])) * rdn;
          f[j] = f2bf(s);
        }
        *(u16x8*)&ctxf[lane][kc*8] = f;
      }
    }
    __syncthreads();   // ctx frags ready
    if (w < 3){
      f32x4 gi0 = {0,0,0,0};
      bf16x8 cf0 = *(const bf16x8*)&ctxf[lane][0];
      bf16x8 cf1 = *(const bf16x8*)&ctxf[lane][8];
      gi0 = MFMA(wih0f[0], cf0, gi0);
      gi0 = MFMA(wih0f[1], cf1, gi0);
#pragma unroll
      for (int r = 0; r < 4; r++) gi0[r] += bih0v[r];
      *(f32x4*)&dslab[w][lane*4] = g0;
      *(f32x4*)&dslab[3+w][lane*4] = gi0;
    }
    __syncthreads();
    if (w == 3){
      f32x4 ghr = *(f32x4*)&dslab[0][lane*4];
      f32x4 ghz = *(f32x4*)&dslab[1][lane*4];
      f32x4 ghn = *(f32x4*)&dslab[2][lane*4];
      f32x4 gir = *(f32x4*)&dslab[3][lane*4];
      f32x4 giz = *(f32x4*)&dslab[4][lane*4];
      f32x4 gin = *(f32x4*)&dslab[5][lane*4];
      f32x4 hn;
#pragma unroll
      for (int r = 0; r < 4; r++){
        float rr = fsig(gir[r] + ghr[r]);
        float zz = fsig(giz[r] + ghz[r]);
        float nn = ftanh(gin[r] + rr*ghn[r]);
        hn[r] = (1.f - zz)*nn + zz*h0p[r];
      }
      h0p = hn;
      const int dp0 = m*8 + quad*2;
      u64* p0 = hb + (long)par*4096 + (dp0>>2)*64 + m16*4 + (dp0&3);
      fire(p0,     packh(sq, hn[0], hn[1]));
      fire(p0 + 1, packh(sq, hn[2], hn[3]));
    }

    // ============ Phase D ============
    // w<3: gh1 = Whh1 . h1(i-1) + bhh1 FIRST (covers part of the h0-exchange;
    // then all waves stage h0 in one poll round).
    f32x4 gh1 = {0,0,0,0};
    if (w < 3){
#pragma unroll
      for (int kc = 0; kc < 16; kc++){
        bf16x8 b1f = *(const bf16x8*)&h1s[kc][lane][0];
        gh1 = MFMA(wf[16+kc], b1f, gh1);
      }
#pragma unroll
      for (int r = 0; r < 4; r++) gh1[r] += bhh1v[r];
    }
    stage_load(hb + (long)par*4096, sq, h0s, tid);
    __syncthreads();
    if (w < 3){
      f32x4 gi1 = {0,0,0,0};
#pragma unroll
      for (int kc = 0; kc < 16; kc++){
        bf16x8 hf = *(const bf16x8*)&h0s[kc][lane][0];
        gi1 = MFMA(wf[32+kc], hf, gi1);
      }
#pragma unroll
      for (int r = 0; r < 4; r++) gi1[r] += bih1v[r];
      *(f32x4*)&dslab[w][lane*4] = gh1;
      *(f32x4*)&dslab[3+w][lane*4] = gi1;
    }
    __syncthreads();
    if (w == 3){
      f32x4 ghr = *(f32x4*)&dslab[0][lane*4];
      f32x4 ghz = *(f32x4*)&dslab[1][lane*4];
      f32x4 ghn = *(f32x4*)&dslab[2][lane*4];
      f32x4 gir = *(f32x4*)&dslab[3][lane*4];
      f32x4 giz = *(f32x4*)&dslab[4][lane*4];
      f32x4 gin = *(f32x4*)&dslab[5][lane*4];
      f32x4 hn;
#pragma unroll
      for (int r = 0; r < 4; r++){
        float rr = fsig(gir[r] + ghr[r]);
        float zz = fsig(giz[r] + ghz[r]);
        float nn = ftanh(gin[r] + rr*ghn[r]);
        hn[r] = (1.f - zz)*nn + zz*h1p[r];
      }
      h1p = hn;
      const int dp0 = m*8 + quad*2;
      u64* p1 = hb + (long)(2 + par)*4096 + (dp0>>2)*64 + m16*4 + (dp0&3);
      fire(p1,     packh(sq, hn[0], hn[1]));
      fire(p1 + 1, packh(sq, hn[2], hn[3]));
      if (i == myidx)
        *(f32x4*)&A_.out[(long)(b0 + m16)*NH + m*16 + quad*4] = hn;
    }
  }
}

// ---------------------------------------------------------------------------
extern "C" void kernel_launch(void* const* d_in, const int* in_sizes, int n_in,
                              void* d_out, int out_size, void* d_ws, size_t ws_size,
                              hipStream_t stream)
{
  (void)in_sizes; (void)n_in; (void)out_size; (void)ws_size;
  char* ws = (char*)d_ws;
  unsigned short* tp     = (unsigned short*)ws;                    // 8 MB
  unsigned short* wqblob = (unsigned short*)(ws + 8388608);        // 64 KB
  u64* hbuf = (u64*)(ws + 8388608 + 65536);                        // 1 MB
  u64* cbuf = hbuf + 8 * (4*4096);                                 // 288 KB

  // 0xFF-fill all seq-tagged slots: tag 0xFFFFFFFF never matches a target
  // seq (<= 513), so garbage/stale data can never be accepted by a poll.
  (void)hipMemsetAsync(hbuf, 0xFF, (size_t)(8*4*4096 + 8*2*2*16*72) * sizeof(u64), stream);

  k_tp<<<dim3(256), dim3(256), 0, stream>>>(
      (const int*)d_in[0], (const float*)d_in[2], (const float*)d_in[3],
      (const float*)d_in[4], tp);
  k_pack<<<dim3(1), dim3(256), 0, stream>>>((const float*)d_in[5], wqblob);

  KArgs ka;
  ka.len  = (const int*)d_in[1];
  ka.bq   = (const float*)d_in[6];
  ka.v    = (const float*)d_in[7];  ka.bv   = (const float*)d_in[8];
  ka.Wih0 = (const float*)d_in[9];  ka.Whh0 = (const float*)d_in[10];
  ka.bih0 = (const float*)d_in[11]; ka.bhh0 = (const float*)d_in[12];
  ka.Wih1 = (const float*)d_in[13]; ka.Whh1 = (const float*)d_in[14];
  ka.bih1 = (const float*)d_in[15]; ka.bhh1 = (const float*)d_in[16];
  ka.tp = tp; ka.wqblob = wqblob;
  ka.hbuf = hbuf; ka.cbuf = cbuf;
  ka.out = (float*)d_out;

  k_main<<<dim3(256), dim3(256), 0, stream>>>(ka);
}

// Round 10
// 6780.651 us; speedup vs baseline: 1.3109x; 1.1411x over previous
//
#include <hip/hip_runtime.h>

#define NB 128
#define NT 512
#define NE 256
#define NH 512
#define NA 64
#define NG 8
#define GB 16

typedef short bf16x8 __attribute__((ext_vector_type(8)));
typedef float f32x4 __attribute__((ext_vector_type(4)));
typedef unsigned short u16x8 __attribute__((ext_vector_type(8)));
typedef unsigned long long u64;

__device__ __forceinline__ unsigned short f2bf(float f){
  unsigned u = __builtin_bit_cast(unsigned, f);
  u = u + 0x7fffu + ((u >> 16) & 1u);
  return (unsigned short)(u >> 16);
}
__device__ __forceinline__ float bf2f(unsigned short h){
  unsigned u = ((unsigned)h) << 16;
  return __builtin_bit_cast(float, u);
}
__device__ __forceinline__ bf16x8 packbf2(f32x4 a, f32x4 b){
  bf16x8 r;
  r[0]=(short)f2bf(a[0]); r[1]=(short)f2bf(a[1]); r[2]=(short)f2bf(a[2]); r[3]=(short)f2bf(a[3]);
  r[4]=(short)f2bf(b[0]); r[5]=(short)f2bf(b[1]); r[6]=(short)f2bf(b[2]); r[7]=(short)f2bf(b[3]);
  return r;
}
__device__ __forceinline__ bf16x8 loadB_f32(const float* p){
  f32x4 a = *(const f32x4*)p;
  f32x4 b = *(const f32x4*)(p + 4);
  return packbf2(a, b);
}
#define MFMA(a,b,c) __builtin_amdgcn_mfma_f32_16x16x32_bf16(a,b,c,0,0,0)

__device__ __forceinline__ float fsig(float x){
  return __builtin_amdgcn_rcpf(1.f + __expf(-x));
}
__device__ __forceinline__ float ftanh(float x){
  float e2 = __expf(2.f * x);
  return 1.f - 2.f * __builtin_amdgcn_rcpf(e2 + 1.f);
}

// s_sleep needs a CONSTANT immediate: constant-ladder backoff.
__device__ __forceinline__ void sleep_bk(int bk){
  if (bk <= 0)      __builtin_amdgcn_s_sleep(1);
  else if (bk == 1) __builtin_amdgcn_s_sleep(2);
  else if (bk == 2) __builtin_amdgcn_s_sleep(4);
  else              __builtin_amdgcn_s_sleep(8);
}

// ---- MALL seq-tagged slot protocol (proven rounds 0-9) ----
__device__ __forceinline__ u64 aload(const u64* p){
  return __hip_atomic_load(p, __ATOMIC_RELAXED, __HIP_MEMORY_SCOPE_AGENT);
}
__device__ __forceinline__ void fire(u64* p, u64 v){
  (void)__hip_atomic_exchange(p, v, __ATOMIC_RELAXED, __HIP_MEMORY_SCOPE_AGENT);
}
__device__ __forceinline__ u64 packh(unsigned sq, float a, float b){
  return ((u64)sq << 32) | ((u64)f2bf(b) << 16) | (u64)f2bf(a);
}
__device__ __forceinline__ u64 packf(unsigned sq, float a){
  return ((u64)sq << 32) | (u64)__builtin_bit_cast(unsigned, a);
}

// ---------------------------------------------------------------------------
__global__ __launch_bounds__(256) void k_tp(
    const int* __restrict__ tok, const float* __restrict__ emb,
    const float* __restrict__ Wt, const float* __restrict__ bt,
    unsigned short* __restrict__ tp)
{
  const int lane = threadIdx.x & 63;
  const int w = threadIdx.x >> 6;
  const int m16 = lane & 15, quad = lane >> 4;

  bf16x8 wfq[8][4];
#pragma unroll
  for (int kc = 0; kc < 8; kc++)
#pragma unroll
    for (int nt = 0; nt < 4; nt++)
      wfq[kc][nt] = loadB_f32(Wt + (nt*16 + m16)*NE + kc*32 + quad*8);

  float btv[4];
#pragma unroll
  for (int nt = 0; nt < 4; nt++) btv[nt] = bt[nt*16 + m16];

  const int gw = blockIdx.x * 4 + w;
#pragma unroll 1
  for (int it = 0; it < 4; it++){
    const int pt = gw * 4 + it;
    const int pos = pt*16 + m16;
    const long row = (long)tok[pos];
    const float* xrow = emb + row * NE;
    f32x4 acc[4] = {{0,0,0,0},{0,0,0,0},{0,0,0,0},{0,0,0,0}};
#pragma unroll
    for (int kc = 0; kc < 8; kc++){
      bf16x8 af = loadB_f32(xrow + kc*32 + quad*8);
#pragma unroll
      for (int nt = 0; nt < 4; nt++)
        acc[nt] = MFMA(af, wfq[kc][nt], acc[nt]);
    }
#pragma unroll
    for (int nt = 0; nt < 4; nt++)
#pragma unroll
      for (int r = 0; r < 4; r++){
        int posr = pt*16 + quad*4 + r;
        tp[(long)posr * NA + nt*16 + m16] = f2bf(acc[nt][r] + btv[nt]);
      }
  }
}

// ---------------------------------------------------------------------------
__global__ __launch_bounds__(256) void k_pack(
    const float* __restrict__ Wq, unsigned short* __restrict__ blob)
{
  const int lane = threadIdx.x & 63, wv = threadIdx.x >> 6;
  const int m16 = lane & 15, quad = lane >> 4;
#pragma unroll
  for (int kc = 0; kc < 16; kc++){
    bf16x8 t = loadB_f32(Wq + (long)(wv*16 + m16)*NH + kc*32 + quad*8);
    *(bf16x8*)&blob[((wv*16 + kc)*64 + lane)*8] = t;
  }
}

// ---------------------------------------------------------------------------
struct KArgs {
  const int* len;
  const float* bq; const float* v; const float* bv;
  const float* Wih0; const float* Whh0; const float* bih0; const float* bhh0;
  const float* Wih1; const float* Whh1; const float* bih1; const float* bhh1;
  const unsigned short* tp;
  const unsigned short* wqblob;
  u64* hbuf;   // [g][stream][state*2+par][2048]; unit idx(dp,b) = dp*8 + b (b<8)
  u64* cbuf;   // [g][stream][par*2+half][16][72]
  float* out;
};

// Poll+stage an 8-batch 512-dim bf16 h-state into fragment-ordered LDS
// [kc][lane][8] (batch cols 0-7). Each thread polls ONE 64B line (dp = tid,
// 8 units = 8 batches of dim-pair tid) -> one dependent RT, bounded retry.
__device__ __forceinline__ void stage8(const u64* __restrict__ buf, unsigned sq,
                                       unsigned short (*hs)[64][8], int tid){
  const u64* u0 = buf + (long)tid * 8;
  u64 x[8];
  int bk = 0;
  for (;;){
    bool ok = true;
#pragma unroll
    for (int j = 0; j < 8; j++) x[j] = aload(u0 + j);
#pragma unroll
    for (int j = 0; j < 8; j++) ok &= ((unsigned)(x[j] >> 32) == sq);
    if (ok) break;
    sleep_bk(bk);
    if (bk < 3) bk++;
  }
  const int kc = tid >> 4, q8 = (tid >> 2) & 3, e0 = (tid & 3) * 2;
#pragma unroll
  for (int b = 0; b < 8; b++)
    *(unsigned*)&hs[kc][q8*16 + b][e0] = (unsigned)x[b];
}

// Two half-streams per group (A = batches 0-7, B = 8-15) advance interleaved:
// every exchange's fire->consume pair has one full phase of the OTHER stream
// between them, halving the exposed MALL round-trip.
__global__ __launch_bounds__(256, 1) void k_main(KArgs A_)
{
  const int tid = threadIdx.x, lane = tid & 63, w = tid >> 6;
  const int g = blockIdx.x & 7, m = blockIdx.x >> 3;   // group, member
  const int m16 = lane & 15, quad = lane >> 4;

  __shared__ __attribute__((aligned(16))) unsigned short h0sA[16][64][8]; // 16KB
  __shared__ __attribute__((aligned(16))) unsigned short h1sA[16][64][8]; // 16KB
  __shared__ __attribute__((aligned(16))) unsigned short h0sB[16][64][8]; // 16KB
  __shared__ __attribute__((aligned(16))) unsigned short h1sB[16][64][8]; // 16KB
  __shared__ __attribute__((aligned(16))) float dslab[6][256];
  __shared__ __attribute__((aligned(16))) float qs[16][68];
  __shared__ __attribute__((aligned(16))) float cslab[4][64];
  __shared__ float cden[4];
  __shared__ __attribute__((aligned(16))) unsigned short ctxf[64][16];

  u64* hbA = A_.hbuf + ((long)g*2 + 0) * (4*2048);
  u64* hbB = A_.hbuf + ((long)g*2 + 1) * (4*2048);
  u64* cbA = A_.cbuf + ((long)g*2 + 0) * (2*2*16*72);
  u64* cbB = A_.cbuf + ((long)g*2 + 1) * (2*2*16*72);
  const int b0 = g * GB;

  // ----- persistent weight fragments (w<3): wf[0..15]=Whh0, [16..31]=Whh1,
  //       [32..47]=Wih1, rows w*512 + m*16 — SHARED by both streams -----
  bf16x8 wf[48], wih0f[2];
  float bhh0v[4], bih0v[4], bhh1v[4], bih1v[4];
  if (w < 3){
    const int r0 = w * NH + m * 16;
#pragma unroll
    for (int kc = 0; kc < 16; kc++){
      wf[kc]    = loadB_f32(A_.Whh0 + (long)(r0 + m16)*NH + kc*32 + quad*8);
      wf[16+kc] = loadB_f32(A_.Whh1 + (long)(r0 + m16)*NH + kc*32 + quad*8);
      wf[32+kc] = loadB_f32(A_.Wih1 + (long)(r0 + m16)*NH + kc*32 + quad*8);
    }
#pragma unroll
    for (int kc = 0; kc < 2; kc++)
      wih0f[kc] = loadB_f32(A_.Wih0 + (r0 + m16)*NA + kc*32 + quad*8);
#pragma unroll
    for (int r = 0; r < 4; r++){
      int d = r0 + quad*4 + r;
      bhh0v[r] = A_.bhh0[d]; bih0v[r] = A_.bih0[d];
      bhh1v[r] = A_.bhh1[d]; bih1v[r] = A_.bih1[d];
    }
  }
  float bqw[4];
#pragma unroll
  for (int r = 0; r < 4; r++) bqw[r] = A_.bq[w*16 + quad*4 + r];

  float vv[16];
#pragma unroll
  for (int jj = 0; jj < 16; jj++) vv[jj] = A_.v[quad*16 + jj];
  const float bvv = A_.bv[0];
  const int abl = (m >> 1) & 7;       // batch-within-stream for owner pair
  const int wr = (m & 1)*4 + w;       // chunk phase 0..7
  const bool ownA = (m < 16), ownB = (m >= 16);

  int myidxA = 0, myidxB = 0, imax = 0;
#pragma unroll 1
  for (int b = 0; b < GB; b++){
    int L = A_.len[b0 + b];
    int ix = L - 2; ix = ix < 0 ? 0 : (ix > NT-1 ? NT-1 : ix);
    if (b == m16)     myidxA = ix;
    if (b == m16 + 8) myidxB = ix;
    imax = imax > ix ? imax : ix;
  }

  f32x4 h0pA = {0,0,0,0}, h1pA = {0,0,0,0};
  f32x4 h0pB = {0,0,0,0}, h1pB = {0,0,0,0};
  f32x4 gh0cA = {0,0,0,0}, gh0cB = {0,0,0,0};
  if (w < 3){
#pragma unroll
    for (int r = 0; r < 4; r++){ gh0cA[r] = bhh0v[r]; gh0cB[r] = bhh0v[r]; }
  }

  // zero LDS h-state: step 0 matmuls yield pure bias (h(-1)=0)
  {
    u16x8 z = {0,0,0,0,0,0,0,0};
#pragma unroll
    for (int c = 0; c < 4; c++){
      int kc = w*4 + c;
      *(u16x8*)&h0sA[kc][lane][0] = z; *(u16x8*)&h1sA[kc][lane][0] = z;
      *(u16x8*)&h0sB[kc][lane][0] = z; *(u16x8*)&h1sB[kc][lane][0] = z;
    }
  }
  __syncthreads();

#pragma unroll 1
  for (int i = 0; i <= imax; i++){
    const int par = i & 1;
    const unsigned sq = (unsigned)(i + 1);
    f32x4 gh1A = {0,0,0,0}, gh1B = {0,0,0,0};

    // ================= P0: stream A front (h1 stage, q, attn, fire ctxA) ====
    if (i > 0) stage8(hbA + (long)(2 + ((i-1)&1))*2048, (unsigned)i, h1sA, tid);
    __syncthreads();
    if (ownA){
      f32x4 qa = {0,0,0,0};
#pragma unroll
      for (int kc = 0; kc < 16; kc++){
        bf16x8 b1f = *(const bf16x8*)&h1sA[kc][lane][0];
        bf16x8 af = *(const bf16x8*)&A_.wqblob[((w*16 + kc)*64 + lane)*8];
        qa = MFMA(af, b1f, qa);
      }
#pragma unroll
      for (int r = 0; r < 4; r++)
        qs[m16][w*16 + quad*4 + r] = qa[r] + bqw[r];
    }
    __syncthreads();
    if (ownA){
      float qv[16];
#pragma unroll
      for (int jq = 0; jq < 4; jq++){
        f32x4 t = *(const f32x4*)&qs[abl][quad*16 + jq*4];
        qv[jq*4+0]=t[0]; qv[jq*4+1]=t[1]; qv[jq*4+2]=t[2]; qv[jq*4+3]=t[3];
      }
      float ctxp[16];
#pragma unroll
      for (int jj = 0; jj < 16; jj++) ctxp[jj] = 0.f;
      float denp = 0.f;
      const unsigned short* tpb = A_.tp + (long)(b0 + abl) * NT * NA;
#pragma unroll 1
      for (int c = wr; c*16 <= i; c += 8){
        const int t = c*16 + m16;
        const unsigned short* tpp = tpb + (long)t*NA + quad*16;
        u16x8 ta = *(const u16x8*)tpp;
        u16x8 tb = *(const u16x8*)(tpp + 8);
        float tpf[16];
#pragma unroll
        for (int jj = 0; jj < 8; jj++){ tpf[jj] = bf2f(ta[jj]); tpf[8+jj] = bf2f(tb[jj]); }
        float sp = 0.f;
#pragma unroll
        for (int jj = 0; jj < 16; jj++){
          float x = tpf[jj] + qv[jj];
          sp = fmaf(ftanh(x), vv[jj], sp);
        }
        sp += __shfl_xor(sp, 16);
        sp += __shfl_xor(sp, 32);
        float e = __expf(sp + bvv);
        e = (t <= i) ? e : 0.f;
        denp += e;
#pragma unroll
        for (int jj = 0; jj < 16; jj++) ctxp[jj] = fmaf(e, tpf[jj], ctxp[jj]);
      }
#pragma unroll
      for (int off = 1; off < 64; off <<= 1) denp += __shfl_xor(denp, off);
      denp *= 0.25f;
#pragma unroll
      for (int st = 0; st < 4; st++){
        const int bit = 1 << st;
        const bool up = (lane >> st) & 1;
        const int n2 = (16 >> st) >> 1;
#pragma unroll
        for (int j2 = 0; j2 < 8; j2++){
          if (j2 < n2){
            float keep = up ? ctxp[2*j2+1] : ctxp[2*j2];
            float send = up ? ctxp[2*j2]   : ctxp[2*j2+1];
            float got = __shfl_xor(send, bit);
            ctxp[j2] = keep + got;
          }
        }
      }
      cslab[w][lane] = ctxp[0];
      if (lane == 0) cden[w] = denp;
    }
    __syncthreads();
    if (ownA && w == 0){
      float s = cslab[0][lane] + cslab[1][lane] + cslab[2][lane] + cslab[3][lane];
      u64* slot = cbA + ((long)(par*2 + (m & 1))*16 + abl)*72;
      fire(slot + lane, packf(sq, s));
      if (lane == 0)
        fire(slot + 64, packf(sq, cden[0]+cden[1]+cden[2]+cden[3]));
    }
    if (w < 3){
#pragma unroll
      for (int kc = 0; kc < 16; kc++){
        bf16x8 b1f = *(const bf16x8*)&h1sA[kc][lane][0];
        gh1A = MFMA(wf[16+kc], b1f, gh1A);
      }
#pragma unroll
      for (int r = 0; r < 4; r++) gh1A[r] += bhh1v[r];
    }

    // ================= P1: stream B front ====================================
    if (i > 0) stage8(hbB + (long)(2 + ((i-1)&1))*2048, (unsigned)i, h1sB, tid);
    __syncthreads();
    if (ownB){
      f32x4 qa = {0,0,0,0};
#pragma unroll
      for (int kc = 0; kc < 16; kc++){
        bf16x8 b1f = *(const bf16x8*)&h1sB[kc][lane][0];
        bf16x8 af = *(const bf16x8*)&A_.wqblob[((w*16 + kc)*64 + lane)*8];
        qa = MFMA(af, b1f, qa);
      }
#pragma unroll
      for (int r = 0; r < 4; r++)
        qs[m16][w*16 + quad*4 + r] = qa[r] + bqw[r];
    }
    __syncthreads();
    if (ownB){
      float qv[16];
#pragma unroll
      for (int jq = 0; jq < 4; jq++){
        f32x4 t = *(const f32x4*)&qs[abl][quad*16 + jq*4];
        qv[jq*4+0]=t[0]; qv[jq*4+1]=t[1]; qv[jq*4+2]=t[2]; qv[jq*4+3]=t[3];
      }
      float ctxp[16];
#pragma unroll
      for (int jj = 0; jj < 16; jj++) ctxp[jj] = 0.f;
      float denp = 0.f;
      const unsigned short* tpb = A_.tp + (long)(b0 + 8 + abl) * NT * NA;
#pragma unroll 1
      for (int c = wr; c*16 <= i; c += 8){
        const int t = c*16 + m16;
        const unsigned short* tpp = tpb + (long)t*NA + quad*16;
        u16x8 ta = *(const u16x8*)tpp;
        u16x8 tb = *(const u16x8*)(tpp + 8);
        float tpf[16];
#pragma unroll
        for (int jj = 0; jj < 8; jj++){ tpf[jj] = bf2f(ta[jj]); tpf[8+jj] = bf2f(tb[jj]); }
        float sp = 0.f;
#pragma unroll
        for (int jj = 0; jj < 16; jj++){
          float x = tpf[jj] + qv[jj];
          sp = fmaf(ftanh(x), vv[jj], sp);
        }
        sp += __shfl_xor(sp, 16);
        sp += __shfl_xor(sp, 32);
        float e = __expf(sp + bvv);
        e = (t <= i) ? e : 0.f;
        denp += e;
#pragma unroll
        for (int jj = 0; jj < 16; jj++) ctxp[jj] = fmaf(e, tpf[jj], ctxp[jj]);
      }
#pragma unroll
      for (int off = 1; off < 64; off <<= 1) denp += __shfl_xor(denp, off);
      denp *= 0.25f;
#pragma unroll
      for (int st = 0; st < 4; st++){
        const int bit = 1 << st;
        const bool up = (lane >> st) & 1;
        const int n2 = (16 >> st) >> 1;
#pragma unroll
        for (int j2 = 0; j2 < 8; j2++){
          if (j2 < n2){
            float keep = up ? ctxp[2*j2+1] : ctxp[2*j2];
            float send = up ? ctxp[2*j2]   : ctxp[2*j2+1];
            float got = __shfl_xor(send, bit);
            ctxp[j2] = keep + got;
          }
        }
      }
      cslab[w][lane] = ctxp[0];
      if (lane == 0) cden[w] = denp;
    }
    __syncthreads();
    if (ownB && w == 0){
      float s = cslab[0][lane] + cslab[1][lane] + cslab[2][lane] + cslab[3][lane];
      u64* slot = cbB + ((long)(par*2 + (m & 1))*16 + abl)*72;
      fire(slot + lane, packf(sq, s));
      if (lane == 0)
        fire(slot + 64, packf(sq, cden[0]+cden[1]+cden[2]+cden[3]));
    }
    if (w < 3){
#pragma unroll
      for (int kc = 0; kc < 16; kc++){
        bf16x8 b1f = *(const bf16x8*)&h1sB[kc][lane][0];
        gh1B = MFMA(wf[16+kc], b1f, gh1B);
      }
#pragma unroll
      for (int r = 0; r < 4; r++) gh1B[r] += bhh1v[r];
    }

    // ================= P2: A ctx -> h0 =======================================
    if (w == 3 && m16 < 8){
      const u64* c0 = cbA + ((long)(par*2 + 0)*16 + m16)*72;
      const u64* c1 = cbA + ((long)(par*2 + 1)*16 + m16)*72;
      u64 d0, d1, t0[16], t1[16];
      int bk = 0;
      for (;;){
        bool ok = true;
        d0 = aload(c0 + 64); d1 = aload(c1 + 64);
#pragma unroll
        for (int kc = 0; kc < 2; kc++){
          const int a0 = kc*32 + quad*8;
#pragma unroll
          for (int j = 0; j < 8; j++){
            t0[kc*8 + j] = aload(c0 + a0 + j);
            t1[kc*8 + j] = aload(c1 + a0 + j);
          }
        }
        ok = ((unsigned)(d0>>32) == sq) & ((unsigned)(d1>>32) == sq);
#pragma unroll
        for (int t = 0; t < 16; t++)
          ok &= ((unsigned)(t0[t]>>32) == sq) & ((unsigned)(t1[t]>>32) == sq);
        if (ok) break;
        sleep_bk(bk);
        if (bk < 3) bk++;
      }
      const float rdn = __builtin_amdgcn_rcpf(
          __builtin_bit_cast(float,(unsigned)d0) + __builtin_bit_cast(float,(unsigned)d1));
#pragma unroll
      for (int kc = 0; kc < 2; kc++){
        u16x8 f;
#pragma unroll
        for (int j = 0; j < 8; j++){
          float s = (__builtin_bit_cast(float,(unsigned)t0[kc*8+j]) +
                     __builtin_bit_cast(float,(unsigned)t1[kc*8+j])) * rdn;
          f[j] = f2bf(s);
        }
        *(u16x8*)&ctxf[lane][kc*8] = f;
      }
    }
    __syncthreads();
    if (w < 3){
      f32x4 gi0 = {0,0,0,0};
      bf16x8 cf0 = *(const bf16x8*)&ctxf[lane][0];
      bf16x8 cf1 = *(const bf16x8*)&ctxf[lane][8];
      gi0 = MFMA(wih0f[0], cf0, gi0);
      gi0 = MFMA(wih0f[1], cf1, gi0);
#pragma unroll
      for (int r = 0; r < 4; r++) gi0[r] += bih0v[r];
      *(f32x4*)&dslab[w][lane*4] = gh0cA;
      *(f32x4*)&dslab[3+w][lane*4] = gi0;
    }
    __syncthreads();
    if (w == 3){
      f32x4 ghr = *(f32x4*)&dslab[0][lane*4];
      f32x4 ghz = *(f32x4*)&dslab[1][lane*4];
      f32x4 ghn = *(f32x4*)&dslab[2][lane*4];
      f32x4 gir = *(f32x4*)&dslab[3][lane*4];
      f32x4 giz = *(f32x4*)&dslab[4][lane*4];
      f32x4 gin = *(f32x4*)&dslab[5][lane*4];
      f32x4 hn;
#pragma unroll
      for (int r = 0; r < 4; r++){
        float rr = fsig(gir[r] + ghr[r]);
        float zz = fsig(giz[r] + ghz[r]);
        float nn = ftanh(gin[r] + rr*ghn[r]);
        hn[r] = (1.f - zz)*nn + zz*h0pA[r];
      }
      h0pA = hn;
      if (m16 < 8){
        const int dp0 = m*8 + quad*2;
        fire(hbA + (long)par*2048 + (long)dp0*8 + m16,     packh(sq, hn[0], hn[1]));
        fire(hbA + (long)par*2048 + (long)(dp0+1)*8 + m16, packh(sq, hn[2], hn[3]));
      }
    }

    // ================= P3: B ctx -> h0 =======================================
    if (w == 3 && m16 < 8){
      const u64* c0 = cbB + ((long)(par*2 + 0)*16 + m16)*72;
      const u64* c1 = cbB + ((long)(par*2 + 1)*16 + m16)*72;
      u64 d0, d1, t0[16], t1[16];
      int bk = 0;
      for (;;){
        bool ok = true;
        d0 = aload(c0 + 64); d1 = aload(c1 + 64);
#pragma unroll
        for (int kc = 0; kc < 2; kc++){
          const int a0 = kc*32 + quad*8;
#pragma unroll
          for (int j = 0; j < 8; j++){
            t0[kc*8 + j] = aload(c0 + a0 + j);
            t1[kc*8 + j] = aload(c1 + a0 + j);
          }
        }
        ok = ((unsigned)(d0>>32) == sq) & ((unsigned)(d1>>32) == sq);
#pragma unroll
        for (int t = 0; t < 16; t++)
          ok &= ((unsigned)(t0[t]>>32) == sq) & ((unsigned)(t1[t]>>32) == sq);
        if (ok) break;
        sleep_bk(bk);
        if (bk < 3) bk++;
      }
      const float rdn = __builtin_amdgcn_rcpf(
          __builtin_bit_cast(float,(unsigned)d0) + __builtin_bit_cast(float,(unsigned)d1));
#pragma unroll
      for (int kc = 0; kc < 2; kc++){
        u16x8 f;
#pragma unroll
        for (int j = 0; j < 8; j++){
          float s = (__builtin_bit_cast(float,(unsigned)t0[kc*8+j]) +
                     __builtin_bit_cast(float,(unsigned)t1[kc*8+j])) * rdn;
          f[j] = f2bf(s);
        }
        *(u16x8*)&ctxf[lane][kc*8] = f;
      }
    }
    __syncthreads();
    if (w < 3){
      f32x4 gi0 = {0,0,0,0};
      bf16x8 cf0 = *(const bf16x8*)&ctxf[lane][0];
      bf16x8 cf1 = *(const bf16x8*)&ctxf[lane][8];
      gi0 = MFMA(wih0f[0], cf0, gi0);
      gi0 = MFMA(wih0f[1], cf1, gi0);
#pragma unroll
      for (int r = 0; r < 4; r++) gi0[r] += bih0v[r];
      *(f32x4*)&dslab[w][lane*4] = gh0cB;
      *(f32x4*)&dslab[3+w][lane*4] = gi0;
    }
    __syncthreads();
    if (w == 3){
      f32x4 ghr = *(f32x4*)&dslab[0][lane*4];
      f32x4 ghz = *(f32x4*)&dslab[1][lane*4];
      f32x4 ghn = *(f32x4*)&dslab[2][lane*4];
      f32x4 gir = *(f32x4*)&dslab[3][lane*4];
      f32x4 giz = *(f32x4*)&dslab[4][lane*4];
      f32x4 gin = *(f32x4*)&dslab[5][lane*4];
      f32x4 hn;
#pragma unroll
      for (int r = 0; r < 4; r++){
        float rr = fsig(gir[r] + ghr[r]);
        float zz = fsig(giz[r] + ghz[r]);
        float nn = ftanh(gin[r] + rr*ghn[r]);
        hn[r] = (1.f - zz)*nn + zz*h0pB[r];
      }
      h0pB = hn;
      if (m16 < 8){
        const int dp0 = m*8 + quad*2;
        fire(hbB + (long)par*2048 + (long)dp0*8 + m16,     packh(sq, hn[0], hn[1]));
        fire(hbB + (long)par*2048 + (long)(dp0+1)*8 + m16, packh(sq, hn[2], hn[3]));
      }
    }

    // ================= P4: A h0 -> h1 ========================================
    stage8(hbA + (long)par*2048, sq, h0sA, tid);
    __syncthreads();
    if (w < 3){
      f32x4 gi1 = {0,0,0,0}, g0 = {0,0,0,0};
#pragma unroll
      for (int kc = 0; kc < 16; kc++){
        bf16x8 hf = *(const bf16x8*)&h0sA[kc][lane][0];
        gi1 = MFMA(wf[32+kc], hf, gi1);
        g0  = MFMA(wf[kc],    hf, g0);
      }
#pragma unroll
      for (int r = 0; r < 4; r++){ gi1[r] += bih1v[r]; gh0cA[r] = g0[r] + bhh0v[r]; }
      *(f32x4*)&dslab[w][lane*4] = gh1A;
      *(f32x4*)&dslab[3+w][lane*4] = gi1;
    }
    __syncthreads();
    if (w == 3){
      f32x4 ghr = *(f32x4*)&dslab[0][lane*4];
      f32x4 ghz = *(f32x4*)&dslab[1][lane*4];
      f32x4 ghn = *(f32x4*)&dslab[2][lane*4];
      f32x4 gir = *(f32x4*)&dslab[3][lane*4];
      f32x4 giz = *(f32x4*)&dslab[4][lane*4];
      f32x4 gin = *(f32x4*)&dslab[5][lane*4];
      f32x4 hn;
#pragma unroll
      for (int r = 0; r < 4; r++){
        float rr = fsig(gir[r] + ghr[r]);
        float zz = fsig(giz[r] + ghz[r]);
        float nn = ftanh(gin[r] + rr*ghn[r]);
        hn[r] = (1.f - zz)*nn + zz*h1pA[r];
      }
      h1pA = hn;
      if (m16 < 8){
        const int dp0 = m*8 + quad*2;
        fire(hbA + (long)(2+par)*2048 + (long)dp0*8 + m16,     packh(sq, hn[0], hn[1]));
        fire(hbA + (long)(2+par)*2048 + (long)(dp0+1)*8 + m16, packh(sq, hn[2], hn[3]));
        if (i == myidxA)
          *(f32x4*)&A_.out[(long)(b0 + m16)*NH + m*16 + quad*4] = hn;
      }
    }

    // ================= P5: B h0 -> h1 ========================================
    stage8(hbB + (long)par*2048, sq, h0sB, tid);
    __syncthreads();
    if (w < 3){
      f32x4 gi1 = {0,0,0,0}, g0 = {0,0,0,0};
#pragma unroll
      for (int kc = 0; kc < 16; kc++){
        bf16x8 hf = *(const bf16x8*)&h0sB[kc][lane][0];
        gi1 = MFMA(wf[32+kc], hf, gi1);
        g0  = MFMA(wf[kc],    hf, g0);
      }
#pragma unroll
      for (int r = 0; r < 4; r++){ gi1[r] += bih1v[r]; gh0cB[r] = g0[r] + bhh0v[r]; }
      *(f32x4*)&dslab[w][lane*4] = gh1B;
      *(f32x4*)&dslab[3+w][lane*4] = gi1;
    }
    __syncthreads();
    if (w == 3){
      f32x4 ghr = *(f32x4*)&dslab[0][lane*4];
      f32x4 ghz = *(f32x4*)&dslab[1][lane*4];
      f32x4 ghn = *(f32x4*)&dslab[2][lane*4];
      f32x4 gir = *(f32x4*)&dslab[3][lane*4];
      f32x4 giz = *(f32x4*)&dslab[4][lane*4];
      f32x4 gin = *(f32x4*)&dslab[5][lane*4];
      f32x4 hn;
#pragma unroll
      for (int r = 0; r < 4; r++){
        float rr = fsig(gir[r] + ghr[r]);
        float zz = fsig(giz[r] + ghz[r]);
        float nn = ftanh(gin[r] + rr*ghn[r]);
        hn[r] = (1.f - zz)*nn + zz*h1pB[r];
      }
      h1pB = hn;
      if (m16 < 8){
        const int dp0 = m*8 + quad*2;
        fire(hbB + (long)(2+par)*2048 + (long)dp0*8 + m16,     packh(sq, hn[0], hn[1]));
        fire(hbB + (long)(2+par)*2048 + (long)(dp0+1)*8 + m16, packh(sq, hn[2], hn[3]));
        if (i == myidxB)
          *(f32x4*)&A_.out[(long)(b0 + 8 + m16)*NH + m*16 + quad*4] = hn;
      }
    }
  }
}

// ---------------------------------------------------------------------------
extern "C" void kernel_launch(void* const* d_in, const int* in_sizes, int n_in,
                              void* d_out, int out_size, void* d_ws, size_t ws_size,
                              hipStream_t stream)
{
  (void)in_sizes; (void)n_in; (void)out_size; (void)ws_size;
  char* ws = (char*)d_ws;
  unsigned short* tp     = (unsigned short*)ws;                    // 8 MB
  unsigned short* wqblob = (unsigned short*)(ws + 8388608);        // 64 KB
  u64* hbuf = (u64*)(ws + 8388608 + 65536);                        // 1 MB
  u64* cbuf = hbuf + 8 * 2 * (4*2048);                             // 576 KB

  // 0xFF-fill all seq-tagged slots: tag 0xFFFFFFFF never matches a target
  // seq (<= 513), so garbage/stale data can never be accepted by a poll.
  (void)hipMemsetAsync(hbuf, 0xFF,
      (size_t)(8*2*4*2048 + 8*2*2*2*16*72) * sizeof(u64), stream);

  k_tp<<<dim3(256), dim3(256), 0, stream>>>(
      (const int*)d_in[0], (const float*)d_in[2], (const float*)d_in[3],
      (const float*)d_in[4], tp);
  k_pack<<<dim3(1), dim3(256), 0, stream>>>((const float*)d_in[5], wqblob);

  KArgs ka;
  ka.len  = (const int*)d_in[1];
  ka.bq   = (const float*)d_in[6];
  ka.v    = (const float*)d_in[7];  ka.bv   = (const float*)d_in[8];
  ka.Wih0 = (const float*)d_in[9];  ka.Whh0 = (const float*)d_in[10];
  ka.bih0 = (const float*)d_in[11]; ka.bhh0 = (const float*)d_in[12];
  ka.Wih1 = (const float*)d_in[13]; ka.Whh1 = (const float*)d_in[14];
  ka.bih1 = (const float*)d_in[15]; ka.bhh1 = (const float*)d_in[16];
  ka.tp = tp; ka.wqblob = wqblob;
  ka.hbuf = hbuf; ka.cbuf = cbuf;
  ka.out = (float*)d_out;

  k_main<<<dim3(256), dim3(256), 0, stream>>>(ka);
}